// Round 1
// baseline (1249.048 us; speedup 1.0000x reference)
//
#include <hip/hip_runtime.h>
#include <cstddef>

#define NB   8
#define NPTS 4096
#define KNN  16

// ---------------------------------------------------------------------------
// Kernel P: pack pts4[b][n] = (x, y, z, x*x+y*y+z*z) from xyz[B][3][N]
// ---------------------------------------------------------------------------
__global__ __launch_bounds__(256) void prep_kernel(const float* __restrict__ xyz,
                                                   float4* __restrict__ pts4) {
    int i = blockIdx.x * 256 + threadIdx.x;       // [0, NB*NPTS)
    int b = i >> 12;
    int n = i & (NPTS - 1);
    const float* base = xyz + (size_t)b * 3 * NPTS;
    float x = base[n];
    float y = base[NPTS + n];
    float z = base[2 * NPTS + n];
    // NOTE: identical fmaf nesting to the dot-product in knn_kernel so that
    // self-distance is exactly 0: sq+sq-2*dot(q,q) == 0 bitwise.
    float sq = fmaf(z, z, fmaf(y, y, x * x));
    pts4[i] = make_float4(x, y, z, sq);
}

// ---------------------------------------------------------------------------
// Kernel A: exact 16-NN per query, brute force over the batch (LDS-resident).
// Phase 1: find 16th-smallest distance (value only, cheap min/max chain).
// Phase 2: rescan, collect {d < tau} then {d == tau} in ascending index order
//          -> exactly jax.lax.top_k's lowest-index tie-break (set-equal).
// ---------------------------------------------------------------------------
__global__ __launch_bounds__(128) void knn_kernel(const float4* __restrict__ pts4,
                                                  int* __restrict__ idxout) {
    __shared__ float4 P[NPTS];                       // 64 KB
    __shared__ unsigned short la[128][16];           // 4 KB  (d <  tau)
    __shared__ unsigned short le[128][16];           // 4 KB  (d == tau)

    int tid = threadIdx.x;
    int b   = blockIdx.y;
    const float4* pb = pts4 + (size_t)b * NPTS;
    for (int i = tid; i < NPTS; i += 128) P[i] = pb[i];
    __syncthreads();

    int n = blockIdx.x * 128 + tid;
    float4 q = P[n];

    float best[16];
#pragma unroll
    for (int j = 0; j < 16; ++j) best[j] = __builtin_inff();

    for (int m = 0; m < NPTS; ++m) {
        float4 p = P[m];
        float dot = fmaf(q.z, p.z, fmaf(q.y, p.y, q.x * p.x));
        float d   = (q.w + p.w) - 2.0f * dot;
        if (d < best[15]) {
            float x = d;
#pragma unroll
            for (int j = 0; j < 16; ++j) {
                float lo = fminf(x, best[j]);
                x        = fmaxf(x, best[j]);
                best[j]  = lo;
            }
        }
    }
    float tau = best[15];

    int cA = 0, cE = 0;
    for (int m = 0; m < NPTS; ++m) {
        float4 p = P[m];
        float dot = fmaf(q.z, p.z, fmaf(q.y, p.y, q.x * p.x));
        float d   = (q.w + p.w) - 2.0f * dot;
        if (d < tau) {
            if (cA < 16) la[tid][cA] = (unsigned short)m;
            ++cA;
        } else if (d == tau) {
            if (cE < 16) { le[tid][cE] = (unsigned short)m; ++cE; }
        }
    }

    int* op = idxout + ((size_t)(b * NPTS + n)) * KNN;
#pragma unroll
    for (int j = 0; j < 16; ++j) {
        int jj = j - cA;
        int v = (j < cA) ? (int)la[tid][j] : (int)le[tid][jj < 0 ? 0 : (jj > 15 ? 15 : jj)];
        op[j] = v;
    }
}

// ---------------------------------------------------------------------------
// Kernel B: fused 3-layer MLP + max over K. One wave per 8 consecutive points.
// lane = channel (0..63). W1 row in VGPRs, W2 transposed in LDS, activations
// bounce through per-wave LDS (wave-synchronous, no block barriers needed).
// ---------------------------------------------------------------------------
__global__ __launch_bounds__(256) void mlp_kernel(
    const float4* __restrict__ pts4, const int* __restrict__ idxin,
    const float* __restrict__ W0, const float* __restrict__ b0,
    const float* __restrict__ W1, const float* __restrict__ b1,
    const float* __restrict__ W2, const float* __restrict__ b2,
    float* __restrict__ out) {
    __shared__ float w2t[64 * 128];       // [c][t2] = W2[t2][c]   32 KB
    __shared__ float hbuf[4][16 * 64];    // per-wave activations  16 KB
    __shared__ float obuf[4][128 * 9];    // per-wave output tile  ~18 KB

    int tid  = threadIdx.x;
    int wave = tid >> 6;
    int lane = tid & 63;

    for (int i = tid; i < 64 * 128; i += 256) {
        int t2 = i >> 6, c = i & 63;
        w2t[c * 128 + t2] = W2[i];
    }
    __syncthreads();

    float w00 = W0[lane * 3 + 0], w01 = W0[lane * 3 + 1], w02 = W0[lane * 3 + 2];
    float b0r = b0[lane], b1r = b1[lane];
    float b2r0 = b2[lane], b2r1 = b2[lane + 64];
    float4 w1r[16];
#pragma unroll
    for (int i = 0; i < 16; ++i) w1r[i] = *(const float4*)(W1 + lane * 64 + i * 4);

    int gw = blockIdx.x * 4 + wave;         // 0..4095
    int b  = gw >> 9;
    int n0 = (gw & 511) * 8;
    const float4* pb = pts4 + (size_t)b * NPTS;
    float* hb = hbuf[wave];
    float* ob = obuf[wave];

    for (int pi = 0; pi < 8; ++pi) {
        int n = n0 + pi;
        float4 q = pb[n];
        const int* ip = idxin + ((size_t)(b * NPTS + n)) * KNN;
        int myidx = ip[lane & 15];
        float4 pk = pb[myidx];
        float rx = pk.x - q.x, ry = pk.y - q.y, rz = pk.z - q.z;

        // layer 0: h0[k][lane] = relu(b0 + W0[lane]·rel[k])
#pragma unroll
        for (int kk = 0; kk < 16; ++kk) {
            float ax = __shfl(rx, kk);
            float ay = __shfl(ry, kk);
            float az = __shfl(rz, kk);
            float h = fmaf(w02, az, fmaf(w01, ay, fmaf(w00, ax, b0r)));
            hb[kk * 64 + lane] = fmaxf(h, 0.0f);
        }

        // layer 1: acc[k] = b1 + sum_c W1[lane][c] * h0[k][c]
        float acc[16];
#pragma unroll
        for (int kk = 0; kk < 16; ++kk) acc[kk] = b1r;
#pragma unroll
        for (int c4 = 0; c4 < 16; ++c4) {
            float4 w = w1r[c4];
#pragma unroll
            for (int kk = 0; kk < 16; ++kk) {
                const float4 h4 = *(const float4*)(hb + kk * 64 + c4 * 4);
                acc[kk] = fmaf(w.w, h4.w, fmaf(w.z, h4.z, fmaf(w.y, h4.y, fmaf(w.x, h4.x, acc[kk]))));
            }
        }
#pragma unroll
        for (int kk = 0; kk < 16; ++kk) hb[kk * 64 + lane] = fmaxf(acc[kk], 0.0f);

        // layer 2: two output channels per lane (lane, lane+64)
        float a0[16], a1[16];
#pragma unroll
        for (int kk = 0; kk < 16; ++kk) { a0[kk] = b2r0; a1[kk] = b2r1; }
#pragma unroll
        for (int c4 = 0; c4 < 16; ++c4) {
            float wa0 = w2t[(c4 * 4 + 0) * 128 + lane];
            float wa1 = w2t[(c4 * 4 + 1) * 128 + lane];
            float wa2 = w2t[(c4 * 4 + 2) * 128 + lane];
            float wa3 = w2t[(c4 * 4 + 3) * 128 + lane];
            float wb0 = w2t[(c4 * 4 + 0) * 128 + lane + 64];
            float wb1 = w2t[(c4 * 4 + 1) * 128 + lane + 64];
            float wb2 = w2t[(c4 * 4 + 2) * 128 + lane + 64];
            float wb3 = w2t[(c4 * 4 + 3) * 128 + lane + 64];
#pragma unroll
            for (int kk = 0; kk < 16; ++kk) {
                const float4 h4 = *(const float4*)(hb + kk * 64 + c4 * 4);
                a0[kk] = fmaf(wa3, h4.w, fmaf(wa2, h4.z, fmaf(wa1, h4.y, fmaf(wa0, h4.x, a0[kk]))));
                a1[kk] = fmaf(wb3, h4.w, fmaf(wb2, h4.z, fmaf(wb1, h4.y, fmaf(wb0, h4.x, a1[kk]))));
            }
        }
        float m0 = a0[0], m1 = a1[0];
#pragma unroll
        for (int kk = 1; kk < 16; ++kk) { m0 = fmaxf(m0, a0[kk]); m1 = fmaxf(m1, a1[kk]); }
        m0 = fmaxf(m0, 0.0f);
        m1 = fmaxf(m1, 0.0f);
        ob[lane * 9 + pi]        = m0;
        ob[(lane + 64) * 9 + pi] = m1;
    }

    // coalesced-ish store of the 128 x 8 tile: out[b][ch][n0..n0+7]
    size_t obase = (size_t)b * 128 * NPTS + n0;
#pragma unroll
    for (int rg = 0; rg < 16; ++rg) {
        int r   = rg * 8 + (lane >> 3);
        int col = lane & 7;
        out[obase + (size_t)r * NPTS + col] = ob[r * 9 + col];
    }
}

// ---------------------------------------------------------------------------
extern "C" void kernel_launch(void* const* d_in, const int* in_sizes, int n_in,
                              void* d_out, int out_size, void* d_ws, size_t ws_size,
                              hipStream_t stream) {
    (void)in_sizes; (void)n_in; (void)out_size; (void)ws_size;
    const float* xyz = (const float*)d_in[0];
    const float* W0  = (const float*)d_in[1];
    const float* b0  = (const float*)d_in[2];
    const float* W1  = (const float*)d_in[3];
    const float* b1  = (const float*)d_in[4];
    const float* W2  = (const float*)d_in[5];
    const float* b2  = (const float*)d_in[6];
    float* out = (float*)d_out;

    char* ws = (char*)d_ws;
    float4* pts4 = (float4*)ws;                                   // 512 KB
    int*    idxb = (int*)(ws + (size_t)NB * NPTS * sizeof(float4)); // 2 MB

    prep_kernel<<<dim3(NB * NPTS / 256), dim3(256), 0, stream>>>(xyz, pts4);
    knn_kernel<<<dim3(NPTS / 128, NB), dim3(128), 0, stream>>>(pts4, idxb);
    mlp_kernel<<<dim3((NB * NPTS / 8) / 4), dim3(256), 0, stream>>>(
        pts4, idxb, W0, b0, W1, b1, W2, b2, out);
}

// Round 2
// 607.503 us; speedup vs baseline: 2.0560x; 2.0560x over previous
//
#include <hip/hip_runtime.h>
#include <cstddef>

#define NB   8
#define NPTS 4096
#define KNN  16

#define QB   128   // queries per block (knn)
#define NCH  8     // candidate chunks per query
#define CHS  512   // chunk size (NCH*CHS == NPTS)

// ---------------------------------------------------------------------------
// Kernel P: pack pts4[b][n] = (x, y, z, x*x+y*y+z*z) from xyz[B][3][N]
// ---------------------------------------------------------------------------
__global__ __launch_bounds__(256) void prep_kernel(const float* __restrict__ xyz,
                                                   float4* __restrict__ pts4) {
    int i = blockIdx.x * 256 + threadIdx.x;       // [0, NB*NPTS)
    int b = i >> 12;
    int n = i & (NPTS - 1);
    const float* base = xyz + (size_t)b * 3 * NPTS;
    float x = base[n];
    float y = base[NPTS + n];
    float z = base[2 * NPTS + n];
    // Identical fmaf nesting to the dot in knn_kernel -> self-distance == 0 exactly.
    float sq = fmaf(z, z, fmaf(y, y, x * x));
    pts4[i] = make_float4(x, y, z, sq);
}

// ---------------------------------------------------------------------------
// Kernel A: exact 16-NN, candidate-split two-phase.
//   block = 1024 thr = 16 waves = 128 queries x 8 chunks of 512 candidates.
//   Phase 1: per (query, chunk) sorted-16 values (cheap min/max chain).
//   Merge : per query, 16th-smallest over 8x16 partials -> tau.
//   Phase 2: per (query, chunk) collect {d<tau} then {d==tau} in index order;
//            concat across chunks == jax.lax.top_k's lowest-index tie-break
//            (set-equal; downstream max-over-K is permutation invariant).
// ---------------------------------------------------------------------------
__global__ __launch_bounds__(1024) void knn_kernel(const float4* __restrict__ pts4,
                                                   int* __restrict__ idxout) {
    __shared__ float4 P[NPTS];                    // 64 KB staged batch
    __shared__ float  scratch[QB * NCH * 16];     // 64 KB: phase-1 partials,
                                                  //        reused as ushort lists[QB][NCH][32]
    __shared__ float  tauv[QB];
    __shared__ int    cnt[QB][NCH];

    int tid = threadIdx.x;
    int b   = blockIdx.y;
    const float4* pb = pts4 + (size_t)b * NPTS;
    for (int i = tid; i < NPTS; i += 1024) P[i] = pb[i];
    __syncthreads();

    int wave = tid >> 6, lane = tid & 63;
    int g = wave >> 3;          // query group 0..1
    int c = wave & 7;           // chunk 0..7
    int q = g * 64 + lane;      // local query 0..127
    int n = blockIdx.x * QB + q;
    float4 Q = P[n];

    // ---- phase 1: sorted-16 distances over this chunk ----
    float best[16];
#pragma unroll
    for (int j = 0; j < 16; ++j) best[j] = __builtin_inff();

    int mbase = c * CHS;
    for (int m = 0; m < CHS; ++m) {
        float4 p = P[mbase + m];
        float dot = fmaf(Q.z, p.z, fmaf(Q.y, p.y, Q.x * p.x));
        float d   = (Q.w + p.w) - 2.0f * dot;
        if (d < best[15]) {
            float x = d;
#pragma unroll
            for (int j = 0; j < 16; ++j) {
                float lo = fminf(x, best[j]);
                x        = fmaxf(x, best[j]);
                best[j]  = lo;
            }
        }
    }
    {
        float* pp = scratch + (q * NCH + c) * 16;
#pragma unroll
        for (int j = 0; j < 16; ++j) pp[j] = best[j];
    }
    __syncthreads();

    // ---- merge: per-query 16th smallest of 8x16 partials -> tau ----
    if (tid < QB) {
        float mb[16];
#pragma unroll
        for (int j = 0; j < 16; ++j) mb[j] = __builtin_inff();
        const float* src = scratch + tid * (NCH * 16);
        // staggered order: spreads banks across lanes; insert is order-invariant
        int rot = (tid & 31) * 4;
        for (int i0 = 0; i0 < NCH * 16; ++i0) {
            int i = (i0 + rot) & (NCH * 16 - 1);
            float d = src[i];
            if (d < mb[15]) {
                float x = d;
#pragma unroll
                for (int j = 0; j < 16; ++j) {
                    float lo = fminf(x, mb[j]);
                    x        = fmaxf(x, mb[j]);
                    mb[j]    = lo;
                }
            }
        }
        tauv[tid] = mb[15];
    }
    __syncthreads();   // tau ready; scratch free for reuse

    // ---- phase 2: collect indices ----
    unsigned short* lst = (unsigned short*)scratch;   // [QB][NCH][32]: A at 0..15, E at 16..31
    unsigned short* myl = lst + (q * NCH + c) * 32;
    float tau = tauv[q];
    int cA = 0, cE = 0;
    for (int m = 0; m < CHS; ++m) {
        float4 p = P[mbase + m];
        float dot = fmaf(Q.z, p.z, fmaf(Q.y, p.y, Q.x * p.x));
        float d   = (Q.w + p.w) - 2.0f * dot;
        if (d < tau) {
            if (cA < 16) myl[cA] = (unsigned short)(mbase + m);
            ++cA;
        } else if (d == tau) {
            if (cE < 16) myl[16 + cE] = (unsigned short)(mbase + m);
            ++cE;
        }
    }
    cnt[q][c] = (cA > 16 ? 16 : cA) | ((cE > 16 ? 16 : cE) << 8);
    __syncthreads();

    // ---- final: concat A-lists (index order), then E-lists, write 16 ints ----
    if (tid < QB) {
        int outpos = 0;
        int* op = idxout + ((size_t)b * NPTS + blockIdx.x * QB + tid) * KNN;
        const unsigned short* L = lst + tid * (NCH * 32);
        for (int cc = 0; cc < NCH; ++cc) {
            int ca = cnt[tid][cc] & 0xff;
            for (int j = 0; j < ca && outpos < 16; ++j) op[outpos++] = (int)L[cc * 32 + j];
        }
        for (int cc = 0; cc < NCH && outpos < 16; ++cc) {
            int ce = (cnt[tid][cc] >> 8) & 0xff;
            for (int j = 0; j < ce && outpos < 16; ++j) op[outpos++] = (int)L[cc * 32 + 16 + j];
        }
    }
}

// ---------------------------------------------------------------------------
// Kernel B: fused 3-layer MLP + max over K (unchanged from round 1).
// ---------------------------------------------------------------------------
__global__ __launch_bounds__(256) void mlp_kernel(
    const float4* __restrict__ pts4, const int* __restrict__ idxin,
    const float* __restrict__ W0, const float* __restrict__ b0,
    const float* __restrict__ W1, const float* __restrict__ b1,
    const float* __restrict__ W2, const float* __restrict__ b2,
    float* __restrict__ out) {
    __shared__ float w2t[64 * 128];       // [c][t2] = W2[t2][c]   32 KB
    __shared__ float hbuf[4][16 * 64];    // per-wave activations  16 KB
    __shared__ float obuf[4][128 * 9];    // per-wave output tile  ~18 KB

    int tid  = threadIdx.x;
    int wave = tid >> 6;
    int lane = tid & 63;

    for (int i = tid; i < 64 * 128; i += 256) {
        int t2 = i >> 6, c = i & 63;
        w2t[c * 128 + t2] = W2[i];
    }
    __syncthreads();

    float w00 = W0[lane * 3 + 0], w01 = W0[lane * 3 + 1], w02 = W0[lane * 3 + 2];
    float b0r = b0[lane], b1r = b1[lane];
    float b2r0 = b2[lane], b2r1 = b2[lane + 64];
    float4 w1r[16];
#pragma unroll
    for (int i = 0; i < 16; ++i) w1r[i] = *(const float4*)(W1 + lane * 64 + i * 4);

    int gw = blockIdx.x * 4 + wave;         // 0..4095
    int b  = gw >> 9;
    int n0 = (gw & 511) * 8;
    const float4* pb = pts4 + (size_t)b * NPTS;
    float* hb = hbuf[wave];
    float* ob = obuf[wave];

    for (int pi = 0; pi < 8; ++pi) {
        int n = n0 + pi;
        float4 q = pb[n];
        const int* ip = idxin + ((size_t)(b * NPTS + n)) * KNN;
        int myidx = ip[lane & 15];
        float4 pk = pb[myidx];
        float rx = pk.x - q.x, ry = pk.y - q.y, rz = pk.z - q.z;

        // layer 0
#pragma unroll
        for (int kk = 0; kk < 16; ++kk) {
            float ax = __shfl(rx, kk);
            float ay = __shfl(ry, kk);
            float az = __shfl(rz, kk);
            float h = fmaf(w02, az, fmaf(w01, ay, fmaf(w00, ax, b0r)));
            hb[kk * 64 + lane] = fmaxf(h, 0.0f);
        }

        // layer 1
        float acc[16];
#pragma unroll
        for (int kk = 0; kk < 16; ++kk) acc[kk] = b1r;
#pragma unroll
        for (int c4 = 0; c4 < 16; ++c4) {
            float4 w = w1r[c4];
#pragma unroll
            for (int kk = 0; kk < 16; ++kk) {
                const float4 h4 = *(const float4*)(hb + kk * 64 + c4 * 4);
                acc[kk] = fmaf(w.w, h4.w, fmaf(w.z, h4.z, fmaf(w.y, h4.y, fmaf(w.x, h4.x, acc[kk]))));
            }
        }
#pragma unroll
        for (int kk = 0; kk < 16; ++kk) hb[kk * 64 + lane] = fmaxf(acc[kk], 0.0f);

        // layer 2: two output channels per lane (lane, lane+64)
        float a0[16], a1[16];
#pragma unroll
        for (int kk = 0; kk < 16; ++kk) { a0[kk] = b2r0; a1[kk] = b2r1; }
#pragma unroll
        for (int c4 = 0; c4 < 16; ++c4) {
            float wa0 = w2t[(c4 * 4 + 0) * 128 + lane];
            float wa1 = w2t[(c4 * 4 + 1) * 128 + lane];
            float wa2 = w2t[(c4 * 4 + 2) * 128 + lane];
            float wa3 = w2t[(c4 * 4 + 3) * 128 + lane];
            float wb0 = w2t[(c4 * 4 + 0) * 128 + lane + 64];
            float wb1 = w2t[(c4 * 4 + 1) * 128 + lane + 64];
            float wb2 = w2t[(c4 * 4 + 2) * 128 + lane + 64];
            float wb3 = w2t[(c4 * 4 + 3) * 128 + lane + 64];
#pragma unroll
            for (int kk = 0; kk < 16; ++kk) {
                const float4 h4 = *(const float4*)(hb + kk * 64 + c4 * 4);
                a0[kk] = fmaf(wa3, h4.w, fmaf(wa2, h4.z, fmaf(wa1, h4.y, fmaf(wa0, h4.x, a0[kk]))));
                a1[kk] = fmaf(wb3, h4.w, fmaf(wb2, h4.z, fmaf(wb1, h4.y, fmaf(wb0, h4.x, a1[kk]))));
            }
        }
        float m0 = a0[0], m1 = a1[0];
#pragma unroll
        for (int kk = 1; kk < 16; ++kk) { m0 = fmaxf(m0, a0[kk]); m1 = fmaxf(m1, a1[kk]); }
        m0 = fmaxf(m0, 0.0f);
        m1 = fmaxf(m1, 0.0f);
        ob[lane * 9 + pi]        = m0;
        ob[(lane + 64) * 9 + pi] = m1;
    }

    size_t obase = (size_t)b * 128 * NPTS + n0;
#pragma unroll
    for (int rg = 0; rg < 16; ++rg) {
        int r   = rg * 8 + (lane >> 3);
        int col = lane & 7;
        out[obase + (size_t)r * NPTS + col] = ob[r * 9 + col];
    }
}

// ---------------------------------------------------------------------------
extern "C" void kernel_launch(void* const* d_in, const int* in_sizes, int n_in,
                              void* d_out, int out_size, void* d_ws, size_t ws_size,
                              hipStream_t stream) {
    (void)in_sizes; (void)n_in; (void)out_size; (void)ws_size;
    const float* xyz = (const float*)d_in[0];
    const float* W0  = (const float*)d_in[1];
    const float* b0  = (const float*)d_in[2];
    const float* W1  = (const float*)d_in[3];
    const float* b1  = (const float*)d_in[4];
    const float* W2  = (const float*)d_in[5];
    const float* b2  = (const float*)d_in[6];
    float* out = (float*)d_out;

    char* ws = (char*)d_ws;
    float4* pts4 = (float4*)ws;                                     // 512 KB
    int*    idxb = (int*)(ws + (size_t)NB * NPTS * sizeof(float4)); // 2 MB

    prep_kernel<<<dim3(NB * NPTS / 256), dim3(256), 0, stream>>>(xyz, pts4);
    knn_kernel<<<dim3(NPTS / QB, NB), dim3(1024), 0, stream>>>(pts4, idxb);
    mlp_kernel<<<dim3((NB * NPTS / 8) / 4), dim3(256), 0, stream>>>(
        pts4, idxb, W0, b0, W1, b1, W2, b2, out);
}

// Round 4
// 328.849 us; speedup vs baseline: 3.7982x; 1.8474x over previous
//
#include <hip/hip_runtime.h>
#include <cstddef>

#define NB   8
#define NPTS 4096
#define KNN  16

#define QB   128   // queries per block (knn)
#define NCH  8     // candidate chunks per query
#define CHS  512   // chunk size (NCH*CHS == NPTS)

typedef _Float16 h2 __attribute__((ext_vector_type(2)));
typedef _Float16 h8 __attribute__((ext_vector_type(8)));
typedef float    f4 __attribute__((ext_vector_type(4)));

static __device__ __forceinline__ h2 pk2(float a, float b) {
    return __builtin_bit_cast(h2, __builtin_amdgcn_cvt_pkrtz(a, b));
}

// ---------------------------------------------------------------------------
// Kernel P: pack pts4[b][n] = (x, y, z, x*x+y*y+z*z) from xyz[B][3][N]
// ---------------------------------------------------------------------------
__global__ __launch_bounds__(256) void prep_kernel(const float* __restrict__ xyz,
                                                   float4* __restrict__ pts4) {
    int i = blockIdx.x * 256 + threadIdx.x;       // [0, NB*NPTS)
    int b = i >> 12;
    int n = i & (NPTS - 1);
    const float* base = xyz + (size_t)b * 3 * NPTS;
    float x = base[n];
    float y = base[NPTS + n];
    float z = base[2 * NPTS + n];
    // Identical fmaf nesting to the dot in knn_kernel -> self-distance == 0 exactly.
    float sq = fmaf(z, z, fmaf(y, y, x * x));
    pts4[i] = make_float4(x, y, z, sq);
}

// ---------------------------------------------------------------------------
// Kernel A: exact 16-NN, candidate-split two-phase (unchanged from round 2).
// ---------------------------------------------------------------------------
__global__ __launch_bounds__(1024) void knn_kernel(const float4* __restrict__ pts4,
                                                   int* __restrict__ idxout) {
    __shared__ float4 P[NPTS];                    // 64 KB staged batch
    __shared__ float  scratch[QB * NCH * 16];     // 64 KB
    __shared__ float  tauv[QB];
    __shared__ int    cnt[QB][NCH];

    int tid = threadIdx.x;
    int b   = blockIdx.y;
    const float4* pb = pts4 + (size_t)b * NPTS;
    for (int i = tid; i < NPTS; i += 1024) P[i] = pb[i];
    __syncthreads();

    int wave = tid >> 6, lane = tid & 63;
    int g = wave >> 3;          // query group 0..1
    int c = wave & 7;           // chunk 0..7
    int q = g * 64 + lane;      // local query 0..127
    int n = blockIdx.x * QB + q;
    float4 Q = P[n];

    float best[16];
#pragma unroll
    for (int j = 0; j < 16; ++j) best[j] = __builtin_inff();

    int mbase = c * CHS;
    for (int m = 0; m < CHS; ++m) {
        float4 p = P[mbase + m];
        float dot = fmaf(Q.z, p.z, fmaf(Q.y, p.y, Q.x * p.x));
        float d   = (Q.w + p.w) - 2.0f * dot;
        if (d < best[15]) {
            float x = d;
#pragma unroll
            for (int j = 0; j < 16; ++j) {
                float lo = fminf(x, best[j]);
                x        = fmaxf(x, best[j]);
                best[j]  = lo;
            }
        }
    }
    {
        float* pp = scratch + (q * NCH + c) * 16;
#pragma unroll
        for (int j = 0; j < 16; ++j) pp[j] = best[j];
    }
    __syncthreads();

    if (tid < QB) {
        float mb[16];
#pragma unroll
        for (int j = 0; j < 16; ++j) mb[j] = __builtin_inff();
        const float* src = scratch + tid * (NCH * 16);
        int rot = (tid & 31) * 4;
        for (int i0 = 0; i0 < NCH * 16; ++i0) {
            int i = (i0 + rot) & (NCH * 16 - 1);
            float d = src[i];
            if (d < mb[15]) {
                float x = d;
#pragma unroll
                for (int j = 0; j < 16; ++j) {
                    float lo = fminf(x, mb[j]);
                    x        = fmaxf(x, mb[j]);
                    mb[j]    = lo;
                }
            }
        }
        tauv[tid] = mb[15];
    }
    __syncthreads();

    unsigned short* lst = (unsigned short*)scratch;   // [QB][NCH][32]
    unsigned short* myl = lst + (q * NCH + c) * 32;
    float tau = tauv[q];
    int cA = 0, cE = 0;
    for (int m = 0; m < CHS; ++m) {
        float4 p = P[mbase + m];
        float dot = fmaf(Q.z, p.z, fmaf(Q.y, p.y, Q.x * p.x));
        float d   = (Q.w + p.w) - 2.0f * dot;
        if (d < tau) {
            if (cA < 16) myl[cA] = (unsigned short)(mbase + m);
            ++cA;
        } else if (d == tau) {
            if (cE < 16) { myl[16 + cE] = (unsigned short)(mbase + m); ++cE; }
        }
    }
    cnt[q][c] = (cA > 16 ? 16 : cA) | ((cE > 16 ? 16 : cE) << 8);
    __syncthreads();

    if (tid < QB) {
        int outpos = 0;
        int* op = idxout + ((size_t)b * NPTS + blockIdx.x * QB + tid) * KNN;
        const unsigned short* L = lst + tid * (NCH * 32);
        for (int cc = 0; cc < NCH; ++cc) {
            int ca = cnt[tid][cc] & 0xff;
            for (int j = 0; j < ca && outpos < 16; ++j) op[outpos++] = (int)L[cc * 32 + j];
        }
        for (int cc = 0; cc < NCH && outpos < 16; ++cc) {
            int ce = (cnt[tid][cc] >> 8) & 0xff;
            for (int j = 0; j < ce && outpos < 16; ++j) op[outpos++] = (int)L[cc * 32 + 16 + j];
        }
    }
}

// ---------------------------------------------------------------------------
// Kernel B: fully-register MFMA MLP. One wave owns 16 points and iterates
// their 16 neighbors. Weights are A-operands (f16 fragments in VGPRs),
// activations are B-operands. Layer transitions are shuffle-free: layer2's
// W2 fragments use a permuted column map `vc` matching the natural register
// order of layer1's D registers (k-placement only needs A/B consistency).
// Max over neighbors is per-lane fmax on D registers.
// ---------------------------------------------------------------------------
__global__ __launch_bounds__(256, 2) void mlp_kernel(
    const float4* __restrict__ pts4, const int* __restrict__ idxin,
    const float* __restrict__ W0, const float* __restrict__ b0,
    const float* __restrict__ W1, const float* __restrict__ b1,
    const float* __restrict__ W2, const float* __restrict__ b2,
    float* __restrict__ out) {

    int tid  = threadIdx.x;
    int wave = tid >> 6, lane = tid & 63;
    int g = lane >> 4, i = lane & 15;

    // ---- one-time fragment setup (all in VGPRs, no LDS) ----
    // layer0 packed-f16 consts: channel pairs (c0, c0+1), c0 = 32s+8g+2v
    h2 w0x[8], w0y[8], w0z[8], w0b[8];
#pragma unroll
    for (int s = 0; s < 2; ++s)
#pragma unroll
        for (int v = 0; v < 4; ++v) {
            int c0 = 32 * s + 8 * g + 2 * v;
            w0x[s * 4 + v] = pk2(W0[c0 * 3 + 0], W0[c0 * 3 + 3]);
            w0y[s * 4 + v] = pk2(W0[c0 * 3 + 1], W0[c0 * 3 + 4]);
            w0z[s * 4 + v] = pk2(W0[c0 * 3 + 2], W0[c0 * 3 + 5]);
            w0b[s * 4 + v] = pk2(b0[c0], b0[c0 + 1]);
        }
    // b1 packed to match the D1->B repack order: word(s,v) covers channels
    // (32s + 16(v>>1) + 4g + 2(v&1), +1)
    h2 b1p[8];
#pragma unroll
    for (int s = 0; s < 2; ++s)
#pragma unroll
        for (int v = 0; v < 4; ++v) {
            int c0 = 32 * s + 16 * (v >> 1) + 4 * g + 2 * (v & 1);
            b1p[s * 4 + v] = pk2(b1[c0], b1[c0 + 1]);
        }
    // W1 A-frags: elem j of (t,s) = W1[16t+i][32s+8g+j]  (natural k-map,
    // matches layer0's B-frag channel map c = 32s+8g+j)
    h8 wf1[4][2];
#pragma unroll
    for (int t = 0; t < 4; ++t)
#pragma unroll
        for (int s = 0; s < 2; ++s) {
            const float* p = W1 + (16 * t + i) * 64 + 32 * s + 8 * g;
            h8 f;
#pragma unroll
            for (int j = 0; j < 8; ++j) f[j] = (_Float16)p[j];
            wf1[t][s] = f;
        }
    // W2 A-frags with permuted k-map: vc(s,g,j) = 32s + 16(j>>2) + 4g + (j&3)
    // (bijective on [0,64), matches H1 B-frag built from D1 regs w/o shuffles)
    h8 wf2[8][2];
#pragma unroll
    for (int t = 0; t < 8; ++t)
#pragma unroll
        for (int s = 0; s < 2; ++s) {
            const float* p = W2 + (16 * t + i) * 64;
            h8 f;
#pragma unroll
            for (int j = 0; j < 8; ++j) {
                int vc = 32 * s + 16 * (j >> 2) + 4 * g + (j & 3);
                f[j] = (_Float16)p[vc];
            }
            wf2[t][s] = f;
        }

    int gw = blockIdx.x * 4 + wave;     // 0..2047 (16 points per wave)
    int b  = gw >> 8;
    int n0 = (gw & 255) * 16;

    const float4* pb = pts4 + (size_t)b * NPTS;
    float4 q = pb[n0 + i];
    const int* ip = idxin + ((size_t)b * NPTS + n0 + i) * KNN;

    float mx[8][4];
#pragma unroll
    for (int t = 0; t < 8; ++t)
#pragma unroll
        for (int r = 0; r < 4; ++r) mx[t][r] = -3.4e38f;

    for (int it = 0; it < KNN; ++it) {
        int mi = ip[it];
        float4 p = pb[mi];
        float rx = p.x - q.x, ry = p.y - q.y, rz = p.z - q.z;
        h2 rxx = pk2(rx, rx), ryy = pk2(ry, ry), rzz = pk2(rz, rz);

        // layer 0 (K=3): packed f16 FMA straight into B-frag layout
        h8 h0f[2];
#pragma unroll
        for (int s = 0; s < 2; ++s)
#pragma unroll
            for (int v = 0; v < 4; ++v) {
                h2 h = __builtin_elementwise_fma(w0z[s * 4 + v], rzz,
                        __builtin_elementwise_fma(w0y[s * 4 + v], ryy,
                         __builtin_elementwise_fma(w0x[s * 4 + v], rxx, w0b[s * 4 + v])));
                h = __builtin_elementwise_max(h, (h2)(_Float16)0.0f);
                h0f[s][2 * v]     = h.x;
                h0f[s][2 * v + 1] = h.y;
            }

        // layer 1: D1[t] (out-ch 16t+4g+r, point i), 8 MFMA
        f4 d1[4];
#pragma unroll
        for (int t = 0; t < 4; ++t) {
            d1[t] = (f4)0.0f;
#pragma unroll
            for (int s = 0; s < 2; ++s)
                d1[t] = __builtin_amdgcn_mfma_f32_16x16x32_f16(wf1[t][s], h0f[s], d1[t], 0, 0, 0);
        }

        // bias + relu + repack to H1 B-frags (no cross-lane moves)
        h8 h1f[2];
#pragma unroll
        for (int s = 0; s < 2; ++s)
#pragma unroll
            for (int v = 0; v < 4; ++v) {
                int t = 2 * s + (v >> 1), r0 = 2 * (v & 1);
                h2 w = pk2(d1[t][r0], d1[t][r0 + 1]);
                w = w + b1p[s * 4 + v];
                w = __builtin_elementwise_max(w, (h2)(_Float16)0.0f);
                h1f[s][2 * v]     = w.x;
                h1f[s][2 * v + 1] = w.y;
            }

        // layer 2: 16 MFMA, bias deferred (relu(max_k s_k + b2) at end)
#pragma unroll
        for (int t = 0; t < 8; ++t) {
            f4 d2 = (f4)0.0f;
#pragma unroll
            for (int s = 0; s < 2; ++s)
                d2 = __builtin_amdgcn_mfma_f32_16x16x32_f16(wf2[t][s], h1f[s], d2, 0, 0, 0);
#pragma unroll
            for (int r = 0; r < 4; ++r) mx[t][r] = fmaxf(mx[t][r], d2[r]);
        }
    }

    // epilogue: bias + relu + store (ch = 16t+4g+r, point n0+i)
    size_t ob = (size_t)b * 128 * NPTS + n0 + i;
#pragma unroll
    for (int t = 0; t < 8; ++t)
#pragma unroll
        for (int r = 0; r < 4; ++r) {
            int ch = 16 * t + 4 * g + r;
            float v = fmaxf(mx[t][r] + b2[ch], 0.0f);
            out[ob + (size_t)ch * NPTS] = v;
        }
}

// ---------------------------------------------------------------------------
extern "C" void kernel_launch(void* const* d_in, const int* in_sizes, int n_in,
                              void* d_out, int out_size, void* d_ws, size_t ws_size,
                              hipStream_t stream) {
    (void)in_sizes; (void)n_in; (void)out_size; (void)ws_size;
    const float* xyz = (const float*)d_in[0];
    const float* W0  = (const float*)d_in[1];
    const float* b0  = (const float*)d_in[2];
    const float* W1  = (const float*)d_in[3];
    const float* b1  = (const float*)d_in[4];
    const float* W2  = (const float*)d_in[5];
    const float* b2  = (const float*)d_in[6];
    float* out = (float*)d_out;

    char* ws = (char*)d_ws;
    float4* pts4 = (float4*)ws;                                     // 512 KB
    int*    idxb = (int*)(ws + (size_t)NB * NPTS * sizeof(float4)); // 2 MB

    prep_kernel<<<dim3(NB * NPTS / 256), dim3(256), 0, stream>>>(xyz, pts4);
    knn_kernel<<<dim3(NPTS / QB, NB), dim3(1024), 0, stream>>>(pts4, idxb);
    mlp_kernel<<<dim3(512), dim3(256), 0, stream>>>(
        pts4, idxb, W0, b0, W1, b1, W2, b2, out);
}

// Round 5
// 178.001 us; speedup vs baseline: 7.0171x; 1.8474x over previous
//
#include <hip/hip_runtime.h>
#include <cstddef>

#define NB   8
#define NPTS 4096
#define KNN  16

#define QB   128   // queries per block (knn)
#define NCH  8     // candidate chunks per query
#define CHS  512   // chunk size (NCH*CHS == NPTS)

typedef _Float16 h2 __attribute__((ext_vector_type(2)));
typedef _Float16 h8 __attribute__((ext_vector_type(8)));
typedef float    f4 __attribute__((ext_vector_type(4)));

static __device__ __forceinline__ h2 pk2(float a, float b) {
    return __builtin_bit_cast(h2, __builtin_amdgcn_cvt_pkrtz(a, b));
}

// One distance formula, explicit fmaf everywhere -> bitwise identical at every
// call site (no contraction freedom). Self-distance is exactly 0 (dot == Q.w).
static __device__ __forceinline__ float dist2(float4 Q, float4 p) {
    float dot = fmaf(Q.z, p.z, fmaf(Q.y, p.y, Q.x * p.x));
    return fmaf(-2.0f, dot, Q.w + p.w);
}

// ---------------------------------------------------------------------------
// Kernel P: pack pts4[b][n] = (x, y, z, x*x+y*y+z*z) from xyz[B][3][N]
// ---------------------------------------------------------------------------
__global__ __launch_bounds__(256) void prep_kernel(const float* __restrict__ xyz,
                                                   float4* __restrict__ pts4) {
    int i = blockIdx.x * 256 + threadIdx.x;       // [0, NB*NPTS)
    int b = i >> 12;
    int n = i & (NPTS - 1);
    const float* base = xyz + (size_t)b * 3 * NPTS;
    float x = base[n];
    float y = base[NPTS + n];
    float z = base[2 * NPTS + n];
    float sq = fmaf(z, z, fmaf(y, y, x * x));   // same nesting as dist2's dot
    pts4[i] = make_float4(x, y, z, sq);
}

// ---------------------------------------------------------------------------
// Kernel A: exact 16-NN, 3-phase with cheap upper-bound tau.
//  Phase 1: per (q,c) lane: top-4 sorted chain per 128-cand subchunk (x4)
//           -> 16 partial values. 16th-smallest of the union >= true tau.
//  Merge  : tid<128: tau_hat = 16th smallest of the 128 partials.
//  Phase 2: collect indices with d <= tau_hat per (q,c) (expected ~2-3/chunk).
//  Final  : tid<128: recompute d for collected (~20), bubble-insert (d,idx)
//           in ascending index order, strict < -> exact top_k tie-break.
// ---------------------------------------------------------------------------
__global__ __launch_bounds__(1024) void knn_kernel(const float4* __restrict__ pts4,
                                                   int* __restrict__ idxout) {
    __shared__ float4 P[NPTS];                    // 64 KB staged batch
    __shared__ float  scratch[QB * NCH * 16];     // 64 KB partials; reused as lists
    __shared__ float  tauv[QB];
    __shared__ int    cnt[QB][NCH];

    int tid = threadIdx.x;
    int b   = blockIdx.y;
    const float4* pb = pts4 + (size_t)b * NPTS;
    for (int i = tid; i < NPTS; i += 1024) P[i] = pb[i];
    __syncthreads();

    int wave = tid >> 6, lane = tid & 63;
    int g = wave >> 3;          // query group 0..1
    int c = wave & 7;           // chunk 0..7
    int q = g * 64 + lane;      // local query 0..127
    int n = blockIdx.x * QB + q;
    float4 Q = P[n];
    int sw = q & 15;            // per-(q,c) slot swizzle (bank spread)

    // ---- phase 1: 4 subchunks x top-4 sorted chain ----
    {
        float* pp = scratch + (q * NCH + c) * 16;
        int mbase = c * CHS;
#pragma unroll
        for (int sc = 0; sc < 4; ++sc) {
            float b0 = __builtin_inff(), b1 = b0, b2 = b0, b3 = b0;
            int m0 = mbase + sc * 128;
#pragma unroll 4
            for (int m = 0; m < 128; ++m) {
                float d = dist2(Q, P[m0 + m]);
                if (d < b3) {
                    float x = d, t;
                    t = fminf(x, b0); x = fmaxf(x, b0); b0 = t;
                    t = fminf(x, b1); x = fmaxf(x, b1); b1 = t;
                    t = fminf(x, b2); x = fmaxf(x, b2); b2 = t;
                    t = fminf(x, b3); x = fmaxf(x, b3); b3 = t;
                }
            }
            pp[(sc * 4 + 0) ^ sw] = b0;
            pp[(sc * 4 + 1) ^ sw] = b1;
            pp[(sc * 4 + 2) ^ sw] = b2;
            pp[(sc * 4 + 3) ^ sw] = b3;
        }
    }
    __syncthreads();

    // ---- merge: tau_hat = 16th smallest of 128 partials ----
    if (tid < QB) {
        float mb[16];
#pragma unroll
        for (int j = 0; j < 16; ++j) mb[j] = __builtin_inff();
        const float* src = scratch + tid * (NCH * 16);
        int swm = tid & 15;
        for (int cc = 0; cc < NCH; ++cc)
#pragma unroll
            for (int k = 0; k < 16; ++k) {
                float d = src[cc * 16 + (k ^ swm)];
                if (d < mb[15]) {
                    float x = d;
#pragma unroll
                    for (int j = 0; j < 16; ++j) {
                        float lo = fminf(x, mb[j]);
                        x        = fmaxf(x, mb[j]);
                        mb[j]    = lo;
                    }
                }
            }
        tauv[tid] = mb[15];
    }
    __syncthreads();   // scratch free for reuse

    // ---- phase 2: collect indices with d <= tau_hat ----
    unsigned short* lst = (unsigned short*)scratch;   // [QB*NCH][16]
    {
        unsigned short* myl = lst + (q * NCH + c) * 16;
        float tau = tauv[q];
        int mbase = c * CHS;
        int cA = 0;
#pragma unroll 4
        for (int m = 0; m < CHS; ++m) {
            float d = dist2(Q, P[mbase + m]);
            if (d <= tau) {
                if (cA < 16) myl[cA] = (unsigned short)(mbase + m);
                ++cA;
            }
        }
        cnt[q][c] = (cA > 16) ? 16 : cA;
    }
    __syncthreads();

    // ---- final: exact top-16 of collected, (d, index-order) semantics ----
    if (tid < QB) {
        float4 Qf = P[blockIdx.x * QB + tid];
        float bd[16]; int bi[16];
#pragma unroll
        for (int j = 0; j < 16; ++j) { bd[j] = __builtin_inff(); bi[j] = 0; }
        for (int cc = 0; cc < NCH; ++cc) {
            int nc = cnt[tid][cc];
            const unsigned short* L = lst + (tid * NCH + cc) * 16;
            for (int j = 0; j < nc; ++j) {
                int idx = (int)L[j];
                float x = dist2(Qf, P[idx]);
                int   xi = idx;
#pragma unroll
                for (int t = 0; t < 16; ++t) {
                    bool cnd = x < bd[t];
                    float nd = cnd ? x  : bd[t];
                    int   ni = cnd ? xi : bi[t];
                    float ox = cnd ? bd[t] : x;
                    int   oi = cnd ? bi[t] : xi;
                    bd[t] = nd; bi[t] = ni; x = ox; xi = oi;
                }
            }
        }
        int* op = idxout + ((size_t)b * NPTS + blockIdx.x * QB + tid) * KNN;
#pragma unroll
        for (int j = 0; j < 16; ++j) op[j] = bi[j];
    }
}

// ---------------------------------------------------------------------------
// Kernel B: fully-register MFMA MLP (unchanged from round 4).
// ---------------------------------------------------------------------------
__global__ __launch_bounds__(256, 2) void mlp_kernel(
    const float4* __restrict__ pts4, const int* __restrict__ idxin,
    const float* __restrict__ W0, const float* __restrict__ b0,
    const float* __restrict__ W1, const float* __restrict__ b1,
    const float* __restrict__ W2, const float* __restrict__ b2,
    float* __restrict__ out) {

    int tid  = threadIdx.x;
    int wave = tid >> 6, lane = tid & 63;
    int g = lane >> 4, i = lane & 15;

    h2 w0x[8], w0y[8], w0z[8], w0b[8];
#pragma unroll
    for (int s = 0; s < 2; ++s)
#pragma unroll
        for (int v = 0; v < 4; ++v) {
            int c0 = 32 * s + 8 * g + 2 * v;
            w0x[s * 4 + v] = pk2(W0[c0 * 3 + 0], W0[c0 * 3 + 3]);
            w0y[s * 4 + v] = pk2(W0[c0 * 3 + 1], W0[c0 * 3 + 4]);
            w0z[s * 4 + v] = pk2(W0[c0 * 3 + 2], W0[c0 * 3 + 5]);
            w0b[s * 4 + v] = pk2(b0[c0], b0[c0 + 1]);
        }
    h2 b1p[8];
#pragma unroll
    for (int s = 0; s < 2; ++s)
#pragma unroll
        for (int v = 0; v < 4; ++v) {
            int c0 = 32 * s + 16 * (v >> 1) + 4 * g + 2 * (v & 1);
            b1p[s * 4 + v] = pk2(b1[c0], b1[c0 + 1]);
        }
    h8 wf1[4][2];
#pragma unroll
    for (int t = 0; t < 4; ++t)
#pragma unroll
        for (int s = 0; s < 2; ++s) {
            const float* p = W1 + (16 * t + i) * 64 + 32 * s + 8 * g;
            h8 f;
#pragma unroll
            for (int j = 0; j < 8; ++j) f[j] = (_Float16)p[j];
            wf1[t][s] = f;
        }
    h8 wf2[8][2];
#pragma unroll
    for (int t = 0; t < 8; ++t)
#pragma unroll
        for (int s = 0; s < 2; ++s) {
            const float* p = W2 + (16 * t + i) * 64;
            h8 f;
#pragma unroll
            for (int j = 0; j < 8; ++j) {
                int vc = 32 * s + 16 * (j >> 2) + 4 * g + (j & 3);
                f[j] = (_Float16)p[vc];
            }
            wf2[t][s] = f;
        }

    int gw = blockIdx.x * 4 + wave;     // 0..2047 (16 points per wave)
    int b  = gw >> 8;
    int n0 = (gw & 255) * 16;

    const float4* pb = pts4 + (size_t)b * NPTS;
    float4 q = pb[n0 + i];
    const int* ip = idxin + ((size_t)b * NPTS + n0 + i) * KNN;

    float mx[8][4];
#pragma unroll
    for (int t = 0; t < 8; ++t)
#pragma unroll
        for (int r = 0; r < 4; ++r) mx[t][r] = -3.4e38f;

    for (int it = 0; it < KNN; ++it) {
        int mi = ip[it];
        float4 p = pb[mi];
        float rx = p.x - q.x, ry = p.y - q.y, rz = p.z - q.z;
        h2 rxx = pk2(rx, rx), ryy = pk2(ry, ry), rzz = pk2(rz, rz);

        h8 h0f[2];
#pragma unroll
        for (int s = 0; s < 2; ++s)
#pragma unroll
            for (int v = 0; v < 4; ++v) {
                h2 h = __builtin_elementwise_fma(w0z[s * 4 + v], rzz,
                        __builtin_elementwise_fma(w0y[s * 4 + v], ryy,
                         __builtin_elementwise_fma(w0x[s * 4 + v], rxx, w0b[s * 4 + v])));
                h = __builtin_elementwise_max(h, (h2)(_Float16)0.0f);
                h0f[s][2 * v]     = h.x;
                h0f[s][2 * v + 1] = h.y;
            }

        f4 d1[4];
#pragma unroll
        for (int t = 0; t < 4; ++t) {
            d1[t] = (f4)0.0f;
#pragma unroll
            for (int s = 0; s < 2; ++s)
                d1[t] = __builtin_amdgcn_mfma_f32_16x16x32_f16(wf1[t][s], h0f[s], d1[t], 0, 0, 0);
        }

        h8 h1f[2];
#pragma unroll
        for (int s = 0; s < 2; ++s)
#pragma unroll
            for (int v = 0; v < 4; ++v) {
                int t = 2 * s + (v >> 1), r0 = 2 * (v & 1);
                h2 w = pk2(d1[t][r0], d1[t][r0 + 1]);
                w = w + b1p[s * 4 + v];
                w = __builtin_elementwise_max(w, (h2)(_Float16)0.0f);
                h1f[s][2 * v]     = w.x;
                h1f[s][2 * v + 1] = w.y;
            }

#pragma unroll
        for (int t = 0; t < 8; ++t) {
            f4 d2 = (f4)0.0f;
#pragma unroll
            for (int s = 0; s < 2; ++s)
                d2 = __builtin_amdgcn_mfma_f32_16x16x32_f16(wf2[t][s], h1f[s], d2, 0, 0, 0);
#pragma unroll
            for (int r = 0; r < 4; ++r) mx[t][r] = fmaxf(mx[t][r], d2[r]);
        }
    }

    size_t ob = (size_t)b * 128 * NPTS + n0 + i;
#pragma unroll
    for (int t = 0; t < 8; ++t)
#pragma unroll
        for (int r = 0; r < 4; ++r) {
            int ch = 16 * t + 4 * g + r;
            float v = fmaxf(mx[t][r] + b2[ch], 0.0f);
            out[ob + (size_t)ch * NPTS] = v;
        }
}

// ---------------------------------------------------------------------------
extern "C" void kernel_launch(void* const* d_in, const int* in_sizes, int n_in,
                              void* d_out, int out_size, void* d_ws, size_t ws_size,
                              hipStream_t stream) {
    (void)in_sizes; (void)n_in; (void)out_size; (void)ws_size;
    const float* xyz = (const float*)d_in[0];
    const float* W0  = (const float*)d_in[1];
    const float* b0  = (const float*)d_in[2];
    const float* W1  = (const float*)d_in[3];
    const float* b1  = (const float*)d_in[4];
    const float* W2  = (const float*)d_in[5];
    const float* b2  = (const float*)d_in[6];
    float* out = (float*)d_out;

    char* ws = (char*)d_ws;
    float4* pts4 = (float4*)ws;                                     // 512 KB
    int*    idxb = (int*)(ws + (size_t)NB * NPTS * sizeof(float4)); // 2 MB

    prep_kernel<<<dim3(NB * NPTS / 256), dim3(256), 0, stream>>>(xyz, pts4);
    knn_kernel<<<dim3(NPTS / QB, NB), dim3(1024), 0, stream>>>(pts4, idxb);
    mlp_kernel<<<dim3(512), dim3(256), 0, stream>>>(
        pts4, idxb, W0, b0, W1, b1, W2, b2, out);
}